// Round 10
// baseline (137.869 us; speedup 1.0000x reference)
//
#include <hip/hip_runtime.h>
#include <hip/hip_bf16.h>

#define EMBED 512
#define NSEQ 2048
#define NROWS 4096

typedef unsigned short u16;
typedef __bf16 bf16x8 __attribute__((ext_vector_type(8)));
typedef float f32x4 __attribute__((ext_vector_type(4)));
typedef unsigned short ushort8 __attribute__((ext_vector_type(8)));

__device__ __forceinline__ u16 f2bf(float f) {
    unsigned u = __float_as_uint(f);
    unsigned r = (u + 0x7FFFu + ((u >> 16) & 1u)) >> 16;
    return (u16)r;
}
__device__ __forceinline__ float bf2f(u16 v) {
    return __uint_as_float((unsigned)v << 16);
}

#define XELEMS    (NROWS * EMBED)     // 2097152
#define WCATELEMS (1536 * EMBED)      // 786432
#define NCONVB    1408                // (XELEMS+WCATELEMS)/8/256

// ---------------------------------------------------------------------------
// prep: x -> bf16, Wq|Wk|Wv -> Wcat bf16.  (R0-verbatim)
// ---------------------------------------------------------------------------
__global__ __launch_bounds__(256) void prep_kernel(
    const float* __restrict__ x,
    const float* __restrict__ Wq, const float* __restrict__ Wk,
    const float* __restrict__ Wv,
    u16* __restrict__ xb, u16* __restrict__ Wcat)
{
    const long long e0 = (long long)(blockIdx.x * 256 + threadIdx.x) * 8;
    const float* src;
    u16* dst;
    if (e0 < XELEMS) {
        src = x + e0; dst = xb + e0;
    } else {
        const long long j = e0 - XELEMS;
        const int row = (int)(j >> 9);
        const int col = (int)(j & 511);
        const int sel = row >> 9;            // 0:Wq 1:Wk 2:Wv
        const int r   = row & 511;
        const float* W = (sel == 0) ? Wq : (sel == 1) ? Wk : Wv;
        src = W + (size_t)r * EMBED + col; dst = Wcat + j;
    }
    float4 a = *(const float4*)(src);
    float4 b = *(const float4*)(src + 4);
    union { u16 u[8]; uint4 v; } p;
    p.u[0] = f2bf(a.x); p.u[1] = f2bf(a.y); p.u[2] = f2bf(a.z); p.u[3] = f2bf(a.w);
    p.u[4] = f2bf(b.x); p.u[5] = f2bf(b.y); p.u[6] = f2bf(b.z); p.u[7] = f2bf(b.w);
    *(uint4*)(dst) = p.v;
}

// ---------------------------------------------------------------------------
// QKV GEMM: 768 blocks, 128x64 tile, BK=64, 24 KB LDS — R0 structure but with
// REGISTER-STAGED PREFETCH: next K-tile's 6x16B loads issue to VGPRs before
// the current tile's ds_read+MFMA, then land via ds_write after the barrier.
// The vmcnt drain that previously serialized each K-step now overlaps compute.
// ---------------------------------------------------------------------------
__global__ __launch_bounds__(256) void gemm_qkv_mfma(
    const u16* __restrict__ A, const u16* __restrict__ W,
    const float* __restrict__ bq, const float* __restrict__ bk,
    const float* __restrict__ bvv,
    u16* __restrict__ QKb, float* __restrict__ Vhead,
    float* __restrict__ vpart)
{
    __shared__ __align__(16) u16 As[128 * 64];   // 16 KB
    __shared__ __align__(16) u16 Bs[64 * 64];    // 8 KB

    const int m0 = (blockIdx.x & 31) * 128;
    const int n0 = (blockIdx.x >> 5) * 64;             // 0..1472
    const int sel = n0 >> 9;
    const float* bias = ((sel == 0) ? bq : (sel == 1) ? bk : bvv) + (n0 & 511);

    const int t    = threadIdx.x;
    const int wave = t >> 6, lane = t & 63;
    const int wm   = wave >> 1, wn = wave & 1;
    const int qd   = lane >> 4, lr = lane & 15;

    const int sr8 = lane >> 3;                 // row-in-8 for staging
    const int sg  = (lane & 7) ^ sr8;          // swizzled global granule
    const int soff = sg * 8;                   // global k offset (elems)

    f32x4 acc[4][2] = {};

    const u16* Ag = A + (size_t)m0 * EMBED;
    const u16* Wg = W + (size_t)n0 * EMBED;

    u16* Adst = As + (size_t)(wave * 8) * 64;
    u16* Bdst = Bs + (size_t)(wave * 8) * 64;
    const u16* Asrc = Ag + (size_t)(wave * 8 + sr8) * EMBED + soff;
    const u16* Bsrc = Wg + (size_t)(wave * 8 + sr8) * EMBED + soff;

    // prologue: tile 0 via direct-to-LDS DMA (one-time drain)
#pragma unroll
    for (int j = 0; j < 4; ++j)
        __builtin_amdgcn_global_load_lds(
            (const __attribute__((address_space(1))) void*)(Asrc + (size_t)j * 32 * EMBED),
            (__attribute__((address_space(3))) void*)(Adst + j * 32 * 64), 16, 0, 0);
#pragma unroll
    for (int j = 0; j < 2; ++j)
        __builtin_amdgcn_global_load_lds(
            (const __attribute__((address_space(1))) void*)(Bsrc + (size_t)j * 32 * EMBED),
            (__attribute__((address_space(3))) void*)(Bdst + j * 32 * 64), 16, 0, 0);
    __syncthreads();

    const int lane16 = lane * 8;               // this lane's 16B slot (u16 elems)
    uint4 ra[4], rb[2];

#pragma unroll
    for (int ki = 0; ki < 8; ++ki) {
        // issue next tile's loads early — latency hides under ds_read+MFMA
        if (ki < 7) {
            const int kc = (ki + 1) * 64;
#pragma unroll
            for (int j = 0; j < 4; ++j)
                ra[j] = *(const uint4*)(Asrc + kc + (size_t)j * 32 * EMBED);
#pragma unroll
            for (int j = 0; j < 2; ++j)
                rb[j] = *(const uint4*)(Bsrc + kc + (size_t)j * 32 * EMBED);
        }

#pragma unroll
        for (int kk = 0; kk < 2; ++kk) {
            const int gr = ((kk * 4 + qd) ^ (lr & 7)) * 8;
            bf16x8 af[4], bfr[2];
#pragma unroll
            for (int i = 0; i < 4; ++i)
                af[i]  = *(const bf16x8*)&As[(wm * 64 + i * 16 + lr) * 64 + gr];
#pragma unroll
            for (int i = 0; i < 2; ++i)
                bfr[i] = *(const bf16x8*)&Bs[(wn * 32 + i * 16 + lr) * 64 + gr];
#pragma unroll
            for (int mi = 0; mi < 4; ++mi)
#pragma unroll
                for (int ni = 0; ni < 2; ++ni)
                    acc[mi][ni] = __builtin_amdgcn_mfma_f32_16x16x32_bf16(
                        af[mi], bfr[ni], acc[mi][ni], 0, 0, 0);
        }

        if (ki < 7) {
            __syncthreads();   // all waves done reading the buffer
            // land staged regs (implicit vmcnt wait on first use — mostly arrived)
#pragma unroll
            for (int j = 0; j < 4; ++j)
                *(uint4*)(Adst + j * 32 * 64 + lane16) = ra[j];
#pragma unroll
            for (int j = 0; j < 2; ++j)
                *(uint4*)(Bdst + j * 32 * 64 + lane16) = rb[j];
            __syncthreads();   // writes visible for next step
        }
    }

    // C/D layout: col=lane&15, row=(lane>>4)*4+reg   (R0-verbatim epilogue)
    if (sel < 2) {
#pragma unroll
        for (int ni = 0; ni < 2; ++ni) {
            const int cl = wn * 32 + ni * 16 + lr;
            const float bb = bias[cl];
#pragma unroll
            for (int mi = 0; mi < 4; ++mi)
#pragma unroll
                for (int e = 0; e < 4; ++e) {
                    const int row = m0 + wm * 64 + mi * 16 + qd * 4 + e;
                    QKb[(size_t)row * 1024 + n0 + cl] = f2bf(acc[mi][ni][e] + bb);
                }
        }
    } else {
        const int batch = m0 >> 11;          // tile never crosses batch
        const int mtb   = (m0 >> 7) & 15;    // m-tile within batch
#pragma unroll
        for (int ni = 0; ni < 2; ++ni) {
            const int cl  = wn * 32 + ni * 16 + lr;
            const int col = (n0 - 1024) + cl;            // 0..511
            const float bb = bias[cl];
            float s = 0.f;
#pragma unroll
            for (int mi = 0; mi < 4; ++mi)
#pragma unroll
                for (int e = 0; e < 4; ++e) {
                    const int row = m0 + wm * 64 + mi * 16 + qd * 4 + e;
                    s += acc[mi][ni][e];
                    if ((row & (NSEQ - 1)) < 3)
                        Vhead[(size_t)batch * 1536 + (row & (NSEQ - 1)) * 512 + col]
                            = acc[mi][ni][e] + bb;
                }
            s += __shfl_xor(s, 16);
            s += __shfl_xor(s, 32);
            if (qd == 0)   // one slot per (batch,col,mtb,wm): written exactly once
                vpart[((size_t)batch * 512 + col) * 32 + mtb * 2 + wm] = s;
        }
    }
}

// ---------------------------------------------------------------------------
// Wsmall (R0-verbatim).
// ---------------------------------------------------------------------------
__global__ __launch_bounds__(256) void wsmall_kernel(
    const float* __restrict__ Vhead, const float* __restrict__ vpart,
    const float* __restrict__ bv,
    const float* __restrict__ Wo, float* __restrict__ WT)
{
    __shared__ float Vsm[4][512];
    const int b  = blockIdx.x >> 6;
    const int jb = blockIdx.x & 63;
    const int t  = threadIdx.x;

    for (int idx = t; idx < 512; idx += 256) {
        const float v0 = Vhead[(size_t)b * 1536 + idx];
        const float v1 = Vhead[(size_t)b * 1536 + 512 + idx];
        const float v2 = Vhead[(size_t)b * 1536 + 1024 + idx];
        float sum = 0.f;
        const float* vp = vpart + ((size_t)b * 512 + idx) * 32;
#pragma unroll
        for (int s = 0; s < 32; ++s) sum += vp[s];
        Vsm[0][idx] = v0; Vsm[1][idx] = v1; Vsm[2][idx] = v2;
        Vsm[3][idx] = sum + (float)NSEQ * bv[idx] - (v0 + v1 + v2);
    }
    __syncthreads();

    const int j  = jb * 8 + (t >> 5);
    const int s  = t & 31;
    const int h  = s >> 2, tt = s & 3;
    const float* Wor = Wo + (size_t)j * EMBED + h * 64;
    const float* vr  = &Vsm[tt][h * 64];
    float acc = 0.f;
#pragma unroll
    for (int c = 0; c < 64; ++c) {
        const int cc = (c + 2 * s) & 63;    // rotate to spread LDS banks
        acc = fmaf(vr[cc], Wor[cc], acc);
    }
    WT[((size_t)b * 512 + j) * 32 + s] = acc;
}

// ---------------------------------------------------------------------------
// Fused attention + K=32 output GEMM (R0-verbatim). 256 blocks x 16 rows.
// ---------------------------------------------------------------------------
__global__ __launch_bounds__(256) void attn_out_kernel(
    const u16* __restrict__ QKb, const float* __restrict__ WT,
    const float* __restrict__ bo, float* __restrict__ out)
{
    __shared__ float E[16][32];
    const int r0   = blockIdx.x * 16;
    const int b    = r0 >> 11;
    const int wave = threadIdx.x >> 6, lane = threadIdx.x & 63;
    const int d0   = lane * 8;

#pragma unroll
    for (int i = 0; i < 4; ++i) {
        const int rl = wave * 4 + i;
        const int r  = r0 + rl;
        const int sr = r & (NSEQ - 1);
        const u16* Qr = QKb + (size_t)r * 1024 + d0;
        const u16* Kr = QKb + (size_t)r * 1024 + 512 + d0;

        ushort8 qv = *(const ushort8*)Qr;
        ushort8 kv = *(const ushort8*)Kr;
        float q[8], k[8];
#pragma unroll
        for (int z = 0; z < 8; ++z) { q[z] = bf2f(qv[z]); k[z] = bf2f(kv[z]); }

        float s1 = 0.f;
#pragma unroll
        for (int z = 0; z < 8; ++z) s1 = fmaf(q[z], k[z], s1);

        float s0 = 0.f, s2 = 0.f;
        if (sr > 0) {
            ushort8 pv = *(const ushort8*)(Kr - 1024);
#pragma unroll
            for (int z = 0; z < 8; ++z) s0 = fmaf(q[z], bf2f(pv[z]), s0);
        }
        if (sr < NSEQ - 1) {
            ushort8 nv = *(const ushort8*)(Kr + 1024);
#pragma unroll
            for (int z = 0; z < 8; ++z) s2 = fmaf(q[z], bf2f(nv[z]), s2);
        }
#pragma unroll
        for (int off = 1; off <= 4; off <<= 1) {
            s0 += __shfl_xor(s0, off);
            s1 += __shfl_xor(s1, off);
            s2 += __shfl_xor(s2, off);
        }
        const float m  = fmaxf(fmaxf(s0, s1), fmaxf(s2, 0.f));
        const float e0 = __expf(s0 - m);
        const float e1 = __expf(s1 - m);
        const float e2 = __expf(s2 - m);
        const float eb = __expf(-m);
        const float rd = 1.f / (e0 + e1 + e2 + (float)(NSEQ - 3) * eb);
        const int h = lane >> 3, jj = lane & 7;
        const float coef = (jj == 0) ? e0 : (jj == 1) ? e1 : (jj == 2) ? e2 : eb;
        if (jj < 4) E[rl][h * 4 + jj] = coef * rd;
    }
    __syncthreads();

    const int j0 = threadIdx.x * 2;
    const float* WTb = WT + (size_t)b * 512 * 32;
    float w0[32], w1[32];
#pragma unroll
    for (int s = 0; s < 32; ++s) {
        w0[s] = WTb[(size_t)j0 * 32 + s];
        w1[s] = WTb[(size_t)(j0 + 1) * 32 + s];
    }
    const float b0 = bo[j0], b1 = bo[j0 + 1];
#pragma unroll
    for (int rl = 0; rl < 16; ++rl) {
        float a0 = b0, a1 = b1;
#pragma unroll
        for (int s = 0; s < 32; ++s) {
            const float e = E[rl][s];
            a0 = fmaf(e, w0[s], a0);
            a1 = fmaf(e, w1[s], a1);
        }
        float2 o = make_float2(a0, a1);
        *(float2*)(out + (size_t)(r0 + rl) * EMBED + j0) = o;
    }
}

extern "C" void kernel_launch(void* const* d_in, const int* in_sizes, int n_in,
                              void* d_out, int out_size, void* d_ws, size_t ws_size,
                              hipStream_t stream)
{
    const float* x  = (const float*)d_in[0];
    const float* Wq = (const float*)d_in[1];
    const float* bq = (const float*)d_in[2];
    const float* Wk = (const float*)d_in[3];
    const float* bk = (const float*)d_in[4];
    const float* Wv = (const float*)d_in[5];
    const float* bv = (const float*)d_in[6];
    const float* Wo = (const float*)d_in[7];
    const float* bo = (const float*)d_in[8];
    float* out = (float*)d_out;

    u16*   QKb   = (u16*)d_ws;                     // 4096*1024 u16 (Q|K bf16)
    u16*   xb    = QKb + (size_t)NROWS * 1024;     // 2097152 bf16
    u16*   Wcat  = xb + XELEMS;                    // 786432 bf16
    float* Vhead = (float*)(Wcat + WCATELEMS);     // 2*3*512 f32
    float* vpart = Vhead + 2 * 3 * 512;            // 2*512*32 f32 (write-once)
    float* WT    = vpart + 2 * 512 * 32;           // 2*512*32 f32

    prep_kernel<<<NCONVB, 256, 0, stream>>>(x, Wq, Wk, Wv, xb, Wcat);
    gemm_qkv_mfma<<<768, 256, 0, stream>>>(xb, Wcat, bq, bk, bv, QKb, Vhead, vpart);
    wsmall_kernel<<<128, 256, 0, stream>>>(Vhead, vpart, bv, Wo, WT);
    attn_out_kernel<<<256, 256, 0, stream>>>(QKb, WT, bo, out);
}